// Round 14
// baseline (184.552 us; speedup 1.0000x reference)
//
#include <hip/hip_runtime.h>

typedef unsigned short u16;
typedef __bf16 bf16x8 __attribute__((ext_vector_type(8)));
typedef float f32x4 __attribute__((ext_vector_type(4)));

#define BATCH 2
#define NSEQ  2048
#define DIMN  1024
#define NH    16
#define DH    64
#define M_    (BATCH * NSEQ)   // 4096 rows of x
#define E_    (3 * DIMN)       // 3072 qkv features
#define K_    DIMN             // 1024 reduction dim
#define QKV_BYTES ((size_t)M_ * E_ * sizeof(u16))
#define XB_ELEMS  ((size_t)M_ * K_)
#define WB_ELEMS  ((size_t)E_ * K_)
#define NEED2     (QKV_BYTES + (XB_ELEMS + WB_ELEMS) * sizeof(u16))  // 39.8 MB

__device__ __forceinline__ u16 f2bf(float f) {
  union { float f; unsigned u; } v; v.f = f;
  unsigned r = v.u + 0x7fffu + ((v.u >> 16) & 1u);
  return (u16)(r >> 16);
}
__device__ __forceinline__ uint4 pack8(const float4 a, const float4 b) {
  union { u16 h[8]; uint4 q; } p;
  p.h[0] = f2bf(a.x); p.h[1] = f2bf(a.y); p.h[2] = f2bf(a.z); p.h[3] = f2bf(a.w);
  p.h[4] = f2bf(b.x); p.h[5] = f2bf(b.y); p.h[6] = f2bf(b.z); p.h[7] = f2bf(b.w);
  return p.q;
}
__device__ __forceinline__ void async16(const void* g, void* lds) {
  __builtin_amdgcn_global_load_lds(
      (const __attribute__((address_space(1))) void*)g,
      (__attribute__((address_space(3))) void*)lds, 16, 0, 0);
}

// ---------------------------------------------------------------------------
// Kernel 0: one-shot fp32 -> bf16 convert of X and W (memory-bound, ~7 us).
// ---------------------------------------------------------------------------
__global__ __launch_bounds__(256, 4)
void convert_bf16(const float* __restrict__ X, const float* __restrict__ W,
                  u16* __restrict__ Xb, u16* __restrict__ Wb) {
  const size_t nx = XB_ELEMS / 8, nw = WB_ELEMS / 8;
  const size_t stride = (size_t)gridDim.x * blockDim.x;
  for (size_t i = blockIdx.x * blockDim.x + threadIdx.x; i < nx; i += stride) {
    const float4 a = *(const float4*)&X[i * 8];
    const float4 b = *(const float4*)&X[i * 8 + 4];
    *(uint4*)&Xb[i * 8] = pack8(a, b);
  }
  for (size_t i = blockIdx.x * blockDim.x + threadIdx.x; i < nw; i += stride) {
    const float4 a = *(const float4*)&W[i * 8];
    const float4 b = *(const float4*)&W[i * 8 + 4];
    *(uint4*)&Wb[i * 8] = pack8(a, b);
  }
}

// ---------------------------------------------------------------------------
// Kernel 1 (r14): 256x256-tile GEMM with DOUBLE-BUFFERED async staging.
// Composition of two correctness-proven pieces:
//   - r10's 256^2 geometry (staging indices, XOR swizzle, 2Mx4N wave decomp,
//     epilogue) -- passed on HW.
//   - r8's dbuf loop transform (barrier -> stage(next,other) -> compute(cur))
//     -- passed on HW; its 128^2 failure was the 3->2 blocks/CU occupancy
//     cut, which CANNOT occur here (256^2 baseline is already 1 block/CU, so
//     128 KB LDS is free).
// r10 post-mortem correction: (512,2) caps VGPR at 256 (2 waves/SIMD), not
// 128 -- ~200 needed, no spills. r10's real costs were exposed stage latency
// (fixed by dbuf: the compiler's vmcnt(0)-before-barrier now drains loads
// issued a full compute-phase earlier) and 192-block/75%-CU coverage (paid,
// but catalog's 2-phase 256^2 reference = 682 TF vs our 330 leaves margin).
// ---------------------------------------------------------------------------
__global__ __launch_bounds__(512, 2)
void qkv_gemm_a(const u16* __restrict__ Xb, const u16* __restrict__ Wb,
                u16* __restrict__ QKV) {
  __shared__ __align__(16) u16 As[2][256 * 64];   // 2 x 32 KB
  __shared__ __align__(16) u16 Bs[2][256 * 64];   // 2 x 32 KB
  const int tid  = threadIdx.x;
  const int wave = tid >> 6, lane = tid & 63;
  const int lin = blockIdx.y * gridDim.x + blockIdx.x;   // 0..191
  const int nl  = (lin & 7) * 24 + (lin >> 3);           // bijective (192%8==0)
  const int m0 = (nl & 15) * 256;                        // gridDim.x == 16
  const int n0 = (nl >> 4) * 256;
  const int wr = wave >> 2;                              // 0..1 -> rows wr*128
  const int wc = wave & 3;                               // 0..3 -> cols wc*64
  const int lcol = lane & 15, lrow = lane >> 4;
  const int lr8 = lane >> 3;
  const int slog = (lane & 7) ^ lr8;

  f32x4 acc[8][4] = {};

  auto stage = [&](int sel, int kk) {
    #pragma unroll
    for (int i = 0; i < 4; ++i) {
      const int g = wave * 4 + i;        // 0..31 (8 rows per group)
      const int r = g * 8 + lr8;         // 0..255
      async16(Xb + (size_t)(m0 + r) * K_ + kk + slog * 8, &As[sel][g * 512]);
      async16(Wb + (size_t)(n0 + r) * K_ + kk + slog * 8, &Bs[sel][g * 512]);
    }
  };

  stage(0, 0);   // prologue fill (only exposed drain)

  for (int k0 = 0; k0 < K_; k0 += 64) {
    const int sel = (k0 >> 6) & 1;
    __syncthreads();                     // drains loads staged into buf[sel]
    if (k0 + 64 < K_) stage(sel ^ 1, k0 + 64);  // fly under compute
    #pragma unroll
    for (int ks = 0; ks < 64; ks += 32) {
      const int segl = (ks >> 3) + lrow;
      bf16x8 af[8], bfr[4];
      #pragma unroll
      for (int i = 0; i < 8; ++i) {
        const int r = wr * 128 + lcol + 16 * i;
        af[i] = *(const bf16x8*)&As[sel][r * 64 + ((segl ^ (r & 7)) * 8)];
      }
      #pragma unroll
      for (int j = 0; j < 4; ++j) {
        const int r = wc * 64 + lcol + 16 * j;
        bfr[j] = *(const bf16x8*)&Bs[sel][r * 64 + ((segl ^ (r & 7)) * 8)];
      }
      #pragma unroll
      for (int i = 0; i < 8; ++i)
        #pragma unroll
        for (int j = 0; j < 4; ++j)
          acc[i][j] = __builtin_amdgcn_mfma_f32_16x16x32_bf16(
              af[i], bfr[j], acc[i][j], 0, 0, 0);
    }
  }

  #pragma unroll
  for (int i = 0; i < 8; ++i)
    #pragma unroll
    for (int j = 0; j < 4; ++j)
      #pragma unroll
      for (int r = 0; r < 4; ++r) {
        const int gm = m0 + wr * 128 + 16 * i + lrow * 4 + r;
        const int gn = n0 + wc * 64 + 16 * j + lcol;
        QKV[(size_t)gm * E_ + gn] = f2bf(acc[i][j][r]);
      }
}

// Fallback GEMM (fused fp32->bf16 staging) if ws too small for Xb/Wb.
__global__ __launch_bounds__(256, 2)
void qkv_gemm_f(const float* __restrict__ X, const float* __restrict__ W,
                u16* __restrict__ QKV) {
  __shared__ __align__(16) u16 As[128 * 64];
  __shared__ __align__(16) u16 Bs[128 * 64];
  const int tid  = threadIdx.x;
  const int wave = tid >> 6, lane = tid & 63;
  const int m0 = blockIdx.x * 128, n0 = blockIdx.y * 128;
  const int wm = (wave >> 1) * 64, wn = (wave & 1) * 64;
  const int lcol = lane & 15, lrow = lane >> 4;
  f32x4 acc[4][4] = {};
  for (int k0 = 0; k0 < K_; k0 += 64) {
    __syncthreads();
    #pragma unroll
    for (int p = 0; p < 4; ++p) {
      const int linear = p * 256 + tid;
      const int r = linear >> 3, s = linear & 7;
      const float4 a0 = *(const float4*)&X[(size_t)(m0 + r) * K_ + k0 + s * 8];
      const float4 a1 = *(const float4*)&X[(size_t)(m0 + r) * K_ + k0 + s * 8 + 4];
      const float4 b0 = *(const float4*)&W[(size_t)(n0 + r) * K_ + k0 + s * 8];
      const float4 b1 = *(const float4*)&W[(size_t)(n0 + r) * K_ + k0 + s * 8 + 4];
      const int ph = (s ^ (r & 7)) * 8;
      *(uint4*)&As[r * 64 + ph] = pack8(a0, a1);
      *(uint4*)&Bs[r * 64 + ph] = pack8(b0, b1);
    }
    __syncthreads();
    #pragma unroll
    for (int ks = 0; ks < 64; ks += 32) {
      const int segl = (ks >> 3) + lrow;
      bf16x8 af[4], bfr[4];
      #pragma unroll
      for (int i = 0; i < 4; ++i) {
        const int r = wm + lcol + 16 * i;
        af[i] = *(const bf16x8*)&As[r * 64 + ((segl ^ (r & 7)) * 8)];
      }
      #pragma unroll
      for (int j = 0; j < 4; ++j) {
        const int r = wn + lcol + 16 * j;
        bfr[j] = *(const bf16x8*)&Bs[r * 64 + ((segl ^ (r & 7)) * 8)];
      }
      #pragma unroll
      for (int i = 0; i < 4; ++i)
        #pragma unroll
        for (int j = 0; j < 4; ++j)
          acc[i][j] = __builtin_amdgcn_mfma_f32_16x16x32_bf16(
              af[i], bfr[j], acc[i][j], 0, 0, 0);
    }
  }
  #pragma unroll
  for (int i = 0; i < 4; ++i)
    #pragma unroll
    for (int j = 0; j < 4; ++j)
      #pragma unroll
      for (int r = 0; r < 4; ++r) {
        const int gm = m0 + wm + 16 * i + lrow * 4 + r;
        const int gn = n0 + wn + 16 * j + lcol;
        QKV[(size_t)gm * E_ + gn] = f2bf(acc[i][j][r]);
      }
}

// ---------------------------------------------------------------------------
// Kernel 2: r13-EXACT attention (best measured: 79.1 us; FROZEN).
// r0 body + Vt stride 72 + setprio + native bf16 cast in softmax.
// ---------------------------------------------------------------------------
__global__ __launch_bounds__(256, 2)
void attn(const u16* __restrict__ QKV, float* __restrict__ Out) {
  __shared__ __align__(16) u16 Ks[64 * 72];
  __shared__ __align__(16) u16 Vt[64 * 72];        // XOR-swizzled, stride 72
  __shared__ __align__(16) u16 Ps[4][32 * 72];     // 32 rows per wave

  const int tid = threadIdx.x, wave = tid >> 6, lane = tid & 63;
  const int b = blockIdx.x >> 4, h = blockIdx.x & 15;
  const int i0 = blockIdx.y * 128;
  const int lcol = lane & 15, lrow = lane >> 4;
  const size_t base = (size_t)b * NSEQ;
  const int qoff = h * DH, koff = DIMN + h * DH, voff = 2 * DIMN + h * DH;
  const int sr = tid >> 3;  // 0..31
  const int sg = tid & 7;
  __bf16* const psb = (__bf16*)&Ps[wave][0];

  bf16x8 ones;
  #pragma unroll
  for (int t = 0; t < 8; ++t) ones[t] = (__bf16)1.0f;

  // Q fragments straight from global (once)
  bf16x8 aq[2][2];
  #pragma unroll
  for (int qi = 0; qi < 2; ++qi)
    #pragma unroll
    for (int ksi = 0; ksi < 2; ++ksi) {
      const int row = i0 + wave * 32 + qi * 16 + lcol;
      aq[qi][ksi] = *(const bf16x8*)&QKV[(base + row) * E_ + qoff +
                                         (ksi * 4 + lrow) * 8];
    }

  // prefetch K/V tile 0
  uint4 kreg[2], vreg[2];
  #pragma unroll
  for (int p = 0; p < 2; ++p) {
    const int row = p * 32 + sr;
    const u16* src = &QKV[(base + row) * E_];
    kreg[p] = *(const uint4*)&src[koff + sg * 8];
    vreg[p] = *(const uint4*)&src[voff + sg * 8];
  }

  f32x4 o[2][4] = {};
  f32x4 lacc[2] = {};

  for (int j0 = 0; j0 < NSEQ; j0 += 64) {
    __syncthreads();
    #pragma unroll
    for (int p = 0; p < 2; ++p) {
      const int row = p * 32 + sr;
      *(uint4*)&Ks[row * 72 + sg * 8] = kreg[p];
      const u16* pv = (const u16*)&vreg[p];
      const int jseg = (row >> 3) & 7, jlo = row & 7;
      #pragma unroll
      for (int t = 0; t < 8; ++t)
        Vt[(sg * 8 + t) * 72 + (((jseg ^ sg) & 7) * 8 + jlo)] = pv[t];
    }
    __syncthreads();

    if (j0 + 64 < NSEQ) {
      #pragma unroll
      for (int p = 0; p < 2; ++p) {
        const int row = p * 32 + sr;
        const u16* src = &QKV[(base + j0 + 64 + row) * E_];
        kreg[p] = *(const uint4*)&src[koff + sg * 8];
        vreg[p] = *(const uint4*)&src[voff + sg * 8];
      }
    }

    // S: [2 qi x 16 q] x 64 j — each bk read feeds 2 MFMAs
    f32x4 s[2][4] = {};
    #pragma unroll
    for (int ksi = 0; ksi < 2; ++ksi) {
      const int seg = ksi * 4 + lrow;
      #pragma unroll
      for (int jt = 0; jt < 4; ++jt) {
        const bf16x8 bk = *(const bf16x8*)&Ks[(jt * 16 + lcol) * 72 + seg * 8];
        __builtin_amdgcn_s_setprio(1);
        #pragma unroll
        for (int qi = 0; qi < 2; ++qi)
          s[qi][jt] = __builtin_amdgcn_mfma_f32_16x16x32_bf16(
              aq[qi][ksi], bk, s[qi][jt], 0, 0, 0);
        __builtin_amdgcn_s_setprio(0);
      }
    }

    // static-base softmax numerator -> Ps (A-layout; native bf16 cast)
    #pragma unroll
    for (int qi = 0; qi < 2; ++qi)
      #pragma unroll
      for (int jt = 0; jt < 4; ++jt)
        #pragma unroll
        for (int r = 0; r < 4; ++r) {
          const float p = __expf(fmaf(s[qi][jt][r], 0.125f, -12.0f));
          psb[(qi * 16 + lrow * 4 + r) * 72 + jt * 16 + lcol] = (__bf16)p;
        }

    // O += P@V ; l += P@1 — each bv read feeds 2 MFMAs
    #pragma unroll
    for (int ksi = 0; ksi < 2; ++ksi) {
      const int seg = ksi * 4 + lrow;
      bf16x8 ap[2];
      #pragma unroll
      for (int qi = 0; qi < 2; ++qi)
        ap[qi] = *(const bf16x8*)&Ps[wave][(qi * 16 + lcol) * 72 + seg * 8];
      __builtin_amdgcn_s_setprio(1);
      #pragma unroll
      for (int dt = 0; dt < 4; ++dt) {
        const int d = dt * 16 + lcol;
        const bf16x8 bv = *(const bf16x8*)&Vt[d * 72 + (((seg ^ (d >> 3)) & 7) * 8)];
        #pragma unroll
        for (int qi = 0; qi < 2; ++qi)
          o[qi][dt] = __builtin_amdgcn_mfma_f32_16x16x32_bf16(
              ap[qi], bv, o[qi][dt], 0, 0, 0);
      }
      #pragma unroll
      for (int qi = 0; qi < 2; ++qi)
        lacc[qi] = __builtin_amdgcn_mfma_f32_16x16x32_bf16(
            ap[qi], ones, lacc[qi], 0, 0, 0);
      __builtin_amdgcn_s_setprio(0);
    }
  }

  // epilogue: FP32 out[b, n*H + h, d] = o / l
  #pragma unroll
  for (int qi = 0; qi < 2; ++qi)
    #pragma unroll
    for (int r = 0; r < 4; ++r) {
      const float inv = 1.0f / lacc[qi][r];
      const int i = i0 + wave * 32 + qi * 16 + lrow * 4 + r;
      #pragma unroll
      for (int dt = 0; dt < 4; ++dt) {
        const int d = dt * 16 + lcol;
        Out[((base + i) * NH + h) * DH + d] = o[qi][dt][r] * inv;
      }
    }
}

extern "C" void kernel_launch(void* const* d_in, const int* in_sizes, int n_in,
                              void* d_out, int out_size, void* d_ws, size_t ws_size,
                              hipStream_t stream) {
  const float* x = (const float*)d_in[0];   // fp32 (2,2048,1024)
  const float* w = (const float*)d_in[1];   // fp32 (3072,1024)
  u16* qkv = (u16*)d_ws;                    // bf16 scratch (24 MB)
  float* out = (float*)d_out;               // fp32 (2, 2048*16, 64)

  if (ws_size < QKV_BYTES) return;

  if (ws_size >= NEED2) {
    u16* Xb = (u16*)((char*)d_ws + QKV_BYTES);
    u16* Wb = Xb + XB_ELEMS;
    convert_bf16<<<1024, 256, 0, stream>>>(x, w, Xb, Wb);
    qkv_gemm_a<<<dim3(M_ / 256, E_ / 256), 512, 0, stream>>>(Xb, Wb, qkv);
  } else {
    qkv_gemm_f<<<dim3(M_ / 128, E_ / 128), 256, 0, stream>>>(x, w, qkv);
  }
  attn<<<dim3(BATCH * NH, NSEQ / 128), 256, 0, stream>>>(qkv, out);
}

// Round 15
// 172.799 us; speedup vs baseline: 1.0680x; 1.0680x over previous
//
#include <hip/hip_runtime.h>

typedef unsigned short u16;
typedef __bf16 bf16x8 __attribute__((ext_vector_type(8)));
typedef float f32x4 __attribute__((ext_vector_type(4)));

#define BATCH 2
#define NSEQ  2048
#define DIMN  1024
#define NH    16
#define DH    64
#define M_    (BATCH * NSEQ)   // 4096 rows of x
#define E_    (3 * DIMN)       // 3072 qkv features
#define K_    DIMN             // 1024 reduction dim
#define QKV_BYTES ((size_t)M_ * E_ * sizeof(u16))
#define XB_ELEMS  ((size_t)M_ * K_)
#define WB_ELEMS  ((size_t)E_ * K_)
#define NEED2     (QKV_BYTES + (XB_ELEMS + WB_ELEMS) * sizeof(u16))  // 39.8 MB

__device__ __forceinline__ u16 f2bf(float f) {
  union { float f; unsigned u; } v; v.f = f;
  unsigned r = v.u + 0x7fffu + ((v.u >> 16) & 1u);
  return (u16)(r >> 16);
}
__device__ __forceinline__ uint4 pack8(const float4 a, const float4 b) {
  union { u16 h[8]; uint4 q; } p;
  p.h[0] = f2bf(a.x); p.h[1] = f2bf(a.y); p.h[2] = f2bf(a.z); p.h[3] = f2bf(a.w);
  p.h[4] = f2bf(b.x); p.h[5] = f2bf(b.y); p.h[6] = f2bf(b.z); p.h[7] = f2bf(b.w);
  return p.q;
}
__device__ __forceinline__ void async16(const void* g, void* lds) {
  __builtin_amdgcn_global_load_lds(
      (const __attribute__((address_space(1))) void*)g,
      (__attribute__((address_space(3))) void*)lds, 16, 0, 0);
}

// ---------------------------------------------------------------------------
// Kernel 0: one-shot fp32 -> bf16 convert of X and W (memory-bound, ~9 us).
// ---------------------------------------------------------------------------
__global__ __launch_bounds__(256, 4)
void convert_bf16(const float* __restrict__ X, const float* __restrict__ W,
                  u16* __restrict__ Xb, u16* __restrict__ Wb) {
  const size_t nx = XB_ELEMS / 8, nw = WB_ELEMS / 8;
  const size_t stride = (size_t)gridDim.x * blockDim.x;
  for (size_t i = blockIdx.x * blockDim.x + threadIdx.x; i < nx; i += stride) {
    const float4 a = *(const float4*)&X[i * 8];
    const float4 b = *(const float4*)&X[i * 8 + 4];
    *(uint4*)&Xb[i * 8] = pack8(a, b);
  }
  for (size_t i = blockIdx.x * blockDim.x + threadIdx.x; i < nw; i += stride) {
    const float4 a = *(const float4*)&W[i * 8];
    const float4 b = *(const float4*)&W[i * 8 + 4];
    *(uint4*)&Wb[i * 8] = pack8(a, b);
  }
}

// ---------------------------------------------------------------------------
// Kernel 1: r9/r13-EXACT GEMM (best measured config). 128x128 tile, BK=64,
// global_load_lds width=16 staging, XCD-bijective swizzle, (256,3).
// GEMM CLOSED after exhaustive in-structure + structural tests:
//   r8 dbuf 128^2: -17us (occupancy 3->2, documented m132 mistake)
//   r9 (256,3): neutral (was already resident)
//   r10 256^2 single-buf: -13us (undersubscription + 8-wave resync)
//   r14 256^2 dbuf: -9us (same structural costs; latency fix insufficient)
// => on the m97 structure's documented shape curve (~320 TF @ K=1024 class).
// ---------------------------------------------------------------------------
__global__ __launch_bounds__(256, 3)
void qkv_gemm_a(const u16* __restrict__ Xb, const u16* __restrict__ Wb,
                u16* __restrict__ QKV) {
  __shared__ __align__(16) u16 As[128 * 64];
  __shared__ __align__(16) u16 Bs[128 * 64];
  const int tid  = threadIdx.x;
  const int wave = tid >> 6, lane = tid & 63;
  const int lin = blockIdx.y * gridDim.x + blockIdx.x;   // 0..767
  const int nl  = (lin & 7) * 96 + (lin >> 3);           // bijective (768%8==0)
  const int m0 = (nl & 31) * 128;                        // gridDim.x == 32
  const int n0 = (nl >> 5) * 128;
  const int wm = (wave >> 1) * 64;
  const int wn = (wave & 1) * 64;
  const int lcol = lane & 15, lrow = lane >> 4;
  const int lr8 = lane >> 3;
  const int slog = (lane & 7) ^ lr8;

  f32x4 acc[4][4] = {};

  for (int k0 = 0; k0 < K_; k0 += 64) {
    __syncthreads();
    #pragma unroll
    for (int i = 0; i < 4; ++i) {
      const int g = wave * 4 + i;
      const int r = g * 8 + lr8;
      async16(Xb + (size_t)(m0 + r) * K_ + k0 + slog * 8, &As[g * 512]);
      async16(Wb + (size_t)(n0 + r) * K_ + k0 + slog * 8, &Bs[g * 512]);
    }
    __syncthreads();
    #pragma unroll
    for (int ks = 0; ks < 64; ks += 32) {
      const int segl = (ks >> 3) + lrow;
      bf16x8 af[4], bfr[4];
      #pragma unroll
      for (int i = 0; i < 4; ++i) {
        const int r = wm + lcol + 16 * i;
        af[i] = *(const bf16x8*)&As[r * 64 + ((segl ^ (r & 7)) * 8)];
      }
      #pragma unroll
      for (int j = 0; j < 4; ++j) {
        const int r = wn + lcol + 16 * j;
        bfr[j] = *(const bf16x8*)&Bs[r * 64 + ((segl ^ (r & 7)) * 8)];
      }
      #pragma unroll
      for (int i = 0; i < 4; ++i)
        #pragma unroll
        for (int j = 0; j < 4; ++j)
          acc[i][j] = __builtin_amdgcn_mfma_f32_16x16x32_bf16(
              af[i], bfr[j], acc[i][j], 0, 0, 0);
    }
  }

  #pragma unroll
  for (int i = 0; i < 4; ++i)
    #pragma unroll
    for (int j = 0; j < 4; ++j)
      #pragma unroll
      for (int r = 0; r < 4; ++r) {
        const int gm = m0 + wm + 16 * i + lrow * 4 + r;
        const int gn = n0 + wn + 16 * j + lcol;
        QKV[(size_t)gm * E_ + gn] = f2bf(acc[i][j][r]);
      }
}

// Fallback GEMM (fused fp32->bf16 staging) if ws too small for Xb/Wb.
__global__ __launch_bounds__(256, 2)
void qkv_gemm_f(const float* __restrict__ X, const float* __restrict__ W,
                u16* __restrict__ QKV) {
  __shared__ __align__(16) u16 As[128 * 64];
  __shared__ __align__(16) u16 Bs[128 * 64];
  const int tid  = threadIdx.x;
  const int wave = tid >> 6, lane = tid & 63;
  const int m0 = blockIdx.x * 128, n0 = blockIdx.y * 128;
  const int wm = (wave >> 1) * 64, wn = (wave & 1) * 64;
  const int lcol = lane & 15, lrow = lane >> 4;
  f32x4 acc[4][4] = {};
  for (int k0 = 0; k0 < K_; k0 += 64) {
    __syncthreads();
    #pragma unroll
    for (int p = 0; p < 4; ++p) {
      const int linear = p * 256 + tid;
      const int r = linear >> 3, s = linear & 7;
      const float4 a0 = *(const float4*)&X[(size_t)(m0 + r) * K_ + k0 + s * 8];
      const float4 a1 = *(const float4*)&X[(size_t)(m0 + r) * K_ + k0 + s * 8 + 4];
      const float4 b0 = *(const float4*)&W[(size_t)(n0 + r) * K_ + k0 + s * 8];
      const float4 b1 = *(const float4*)&W[(size_t)(n0 + r) * K_ + k0 + s * 8 + 4];
      const int ph = (s ^ (r & 7)) * 8;
      *(uint4*)&As[r * 64 + ph] = pack8(a0, a1);
      *(uint4*)&Bs[r * 64 + ph] = pack8(b0, b1);
    }
    __syncthreads();
    #pragma unroll
    for (int ks = 0; ks < 64; ks += 32) {
      const int segl = (ks >> 3) + lrow;
      bf16x8 af[4], bfr[4];
      #pragma unroll
      for (int i = 0; i < 4; ++i) {
        const int r = wm + lcol + 16 * i;
        af[i] = *(const bf16x8*)&As[r * 64 + ((segl ^ (r & 7)) * 8)];
      }
      #pragma unroll
      for (int j = 0; j < 4; ++j) {
        const int r = wn + lcol + 16 * j;
        bfr[j] = *(const bf16x8*)&Bs[r * 64 + ((segl ^ (r & 7)) * 8)];
      }
      #pragma unroll
      for (int i = 0; i < 4; ++i)
        #pragma unroll
        for (int j = 0; j < 4; ++j)
          acc[i][j] = __builtin_amdgcn_mfma_f32_16x16x32_bf16(
              af[i], bfr[j], acc[i][j], 0, 0, 0);
    }
  }
  #pragma unroll
  for (int i = 0; i < 4; ++i)
    #pragma unroll
    for (int j = 0; j < 4; ++j)
      #pragma unroll
      for (int r = 0; r < 4; ++r) {
        const int gm = m0 + wm + 16 * i + lrow * 4 + r;
        const int gn = n0 + wn + 16 * j + lcol;
        QKV[(size_t)gm * E_ + gn] = f2bf(acc[i][j][r]);
      }
}

// ---------------------------------------------------------------------------
// Kernel 2: r13-EXACT attention (best measured: 79.1 us; FROZEN).
// r0 body + Vt stride 72 (bank-rotation fix, +3%) + s_setprio around MFMA
// clusters + native bf16 cast in softmax (HW v_cvt, +3%). Bound by per-CU
// LDS-instruction issue at the 8-waves/CU TLP floor the problem imposes;
// all structural alternatives tested r1-r12 lost to this body.
// ---------------------------------------------------------------------------
__global__ __launch_bounds__(256, 2)
void attn(const u16* __restrict__ QKV, float* __restrict__ Out) {
  __shared__ __align__(16) u16 Ks[64 * 72];
  __shared__ __align__(16) u16 Vt[64 * 72];        // XOR-swizzled, stride 72
  __shared__ __align__(16) u16 Ps[4][32 * 72];     // 32 rows per wave

  const int tid = threadIdx.x, wave = tid >> 6, lane = tid & 63;
  const int b = blockIdx.x >> 4, h = blockIdx.x & 15;
  const int i0 = blockIdx.y * 128;
  const int lcol = lane & 15, lrow = lane >> 4;
  const size_t base = (size_t)b * NSEQ;
  const int qoff = h * DH, koff = DIMN + h * DH, voff = 2 * DIMN + h * DH;
  const int sr = tid >> 3;  // 0..31
  const int sg = tid & 7;
  __bf16* const psb = (__bf16*)&Ps[wave][0];

  bf16x8 ones;
  #pragma unroll
  for (int t = 0; t < 8; ++t) ones[t] = (__bf16)1.0f;

  // Q fragments straight from global (once)
  bf16x8 aq[2][2];
  #pragma unroll
  for (int qi = 0; qi < 2; ++qi)
    #pragma unroll
    for (int ksi = 0; ksi < 2; ++ksi) {
      const int row = i0 + wave * 32 + qi * 16 + lcol;
      aq[qi][ksi] = *(const bf16x8*)&QKV[(base + row) * E_ + qoff +
                                         (ksi * 4 + lrow) * 8];
    }

  // prefetch K/V tile 0
  uint4 kreg[2], vreg[2];
  #pragma unroll
  for (int p = 0; p < 2; ++p) {
    const int row = p * 32 + sr;
    const u16* src = &QKV[(base + row) * E_];
    kreg[p] = *(const uint4*)&src[koff + sg * 8];
    vreg[p] = *(const uint4*)&src[voff + sg * 8];
  }

  f32x4 o[2][4] = {};
  f32x4 lacc[2] = {};

  for (int j0 = 0; j0 < NSEQ; j0 += 64) {
    __syncthreads();
    #pragma unroll
    for (int p = 0; p < 2; ++p) {
      const int row = p * 32 + sr;
      *(uint4*)&Ks[row * 72 + sg * 8] = kreg[p];
      const u16* pv = (const u16*)&vreg[p];
      const int jseg = (row >> 3) & 7, jlo = row & 7;
      #pragma unroll
      for (int t = 0; t < 8; ++t)
        Vt[(sg * 8 + t) * 72 + (((jseg ^ sg) & 7) * 8 + jlo)] = pv[t];
    }
    __syncthreads();

    if (j0 + 64 < NSEQ) {
      #pragma unroll
      for (int p = 0; p < 2; ++p) {
        const int row = p * 32 + sr;
        const u16* src = &QKV[(base + j0 + 64 + row) * E_];
        kreg[p] = *(const uint4*)&src[koff + sg * 8];
        vreg[p] = *(const uint4*)&src[voff + sg * 8];
      }
    }

    // S: [2 qi x 16 q] x 64 j — each bk read feeds 2 MFMAs
    f32x4 s[2][4] = {};
    #pragma unroll
    for (int ksi = 0; ksi < 2; ++ksi) {
      const int seg = ksi * 4 + lrow;
      #pragma unroll
      for (int jt = 0; jt < 4; ++jt) {
        const bf16x8 bk = *(const bf16x8*)&Ks[(jt * 16 + lcol) * 72 + seg * 8];
        __builtin_amdgcn_s_setprio(1);
        #pragma unroll
        for (int qi = 0; qi < 2; ++qi)
          s[qi][jt] = __builtin_amdgcn_mfma_f32_16x16x32_bf16(
              aq[qi][ksi], bk, s[qi][jt], 0, 0, 0);
        __builtin_amdgcn_s_setprio(0);
      }
    }

    // static-base softmax numerator -> Ps (A-layout; native bf16 cast)
    #pragma unroll
    for (int qi = 0; qi < 2; ++qi)
      #pragma unroll
      for (int jt = 0; jt < 4; ++jt)
        #pragma unroll
        for (int r = 0; r < 4; ++r) {
          const float p = __expf(fmaf(s[qi][jt][r], 0.125f, -12.0f));
          psb[(qi * 16 + lrow * 4 + r) * 72 + jt * 16 + lcol] = (__bf16)p;
        }

    // O += P@V ; l += P@1 — each bv read feeds 2 MFMAs
    #pragma unroll
    for (int ksi = 0; ksi < 2; ++ksi) {
      const int seg = ksi * 4 + lrow;
      bf16x8 ap[2];
      #pragma unroll
      for (int qi = 0; qi < 2; ++qi)
        ap[qi] = *(const bf16x8*)&Ps[wave][(qi * 16 + lcol) * 72 + seg * 8];
      __builtin_amdgcn_s_setprio(1);
      #pragma unroll
      for (int dt = 0; dt < 4; ++dt) {
        const int d = dt * 16 + lcol;
        const bf16x8 bv = *(const bf16x8*)&Vt[d * 72 + (((seg ^ (d >> 3)) & 7) * 8)];
        #pragma unroll
        for (int qi = 0; qi < 2; ++qi)
          o[qi][dt] = __builtin_amdgcn_mfma_f32_16x16x32_bf16(
              ap[qi], bv, o[qi][dt], 0, 0, 0);
      }
      #pragma unroll
      for (int qi = 0; qi < 2; ++qi)
        lacc[qi] = __builtin_amdgcn_mfma_f32_16x16x32_bf16(
            ap[qi], ones, lacc[qi], 0, 0, 0);
      __builtin_amdgcn_s_setprio(0);
    }
  }

  // epilogue: FP32 out[b, n*H + h, d] = o / l
  #pragma unroll
  for (int qi = 0; qi < 2; ++qi)
    #pragma unroll
    for (int r = 0; r < 4; ++r) {
      const float inv = 1.0f / lacc[qi][r];
      const int i = i0 + wave * 32 + qi * 16 + lrow * 4 + r;
      #pragma unroll
      for (int dt = 0; dt < 4; ++dt) {
        const int d = dt * 16 + lcol;
        Out[((base + i) * NH + h) * DH + d] = o[qi][dt][r] * inv;
      }
    }
}

extern "C" void kernel_launch(void* const* d_in, const int* in_sizes, int n_in,
                              void* d_out, int out_size, void* d_ws, size_t ws_size,
                              hipStream_t stream) {
  const float* x = (const float*)d_in[0];   // fp32 (2,2048,1024)
  const float* w = (const float*)d_in[1];   // fp32 (3072,1024)
  u16* qkv = (u16*)d_ws;                    // bf16 scratch (24 MB)
  float* out = (float*)d_out;               // fp32 (2, 2048*16, 64)

  if (ws_size < QKV_BYTES) return;

  if (ws_size >= NEED2) {
    u16* Xb = (u16*)((char*)d_ws + QKV_BYTES);
    u16* Wb = Xb + XB_ELEMS;
    convert_bf16<<<1024, 256, 0, stream>>>(x, w, Xb, Wb);
    qkv_gemm_a<<<dim3(M_ / 128, E_ / 128), 256, 0, stream>>>(Xb, Wb, qkv);
  } else {
    qkv_gemm_f<<<dim3(M_ / 128, E_ / 128), 256, 0, stream>>>(x, w, qkv);
  }
  attn<<<dim3(BATCH * NH, NSEQ / 128), 256, 0, stream>>>(qkv, out);
}